// Round 7
// baseline (376.571 us; speedup 1.0000x reference)
//
#include <hip/hip_runtime.h>

// ---------------------------------------------------------------------------
// TemperSeq2Seq: enc mean-pool -> tanh linear -> 128-step GRU -> 32000-proj
// B=32, S_SRC=256, S_DEC=128, H=256, V=32000
// Scan: batch-split, standalone (no contention). Proj: Wo-resident LDS tiles.
// ---------------------------------------------------------------------------

typedef __attribute__((ext_vector_type(8))) _Float16 f16x8;
typedef __attribute__((ext_vector_type(2))) _Float16 f16x2;
typedef __attribute__((ext_vector_type(4))) float f32x4;
typedef unsigned short u16;

__device__ __forceinline__ u16 f2h_bits(float v) {
  _Float16 h = (_Float16)v;
  return __builtin_bit_cast(u16, h);
}

#if __has_builtin(__builtin_amdgcn_fdot2)
#define FDOT2(a, b, c) __builtin_amdgcn_fdot2((a), (b), (c), false)
#else
#define FDOT2(a, b, c) \
  ((c) + (float)(a)[0] * (float)(b)[0] + (float)(a)[1] * (float)(b)[1])
#endif

// ---------------- fused: {enc mean-pool + z} (blocks 0..31) ----------------
//                  {fp32->fp16 W_hh/Wo convert} (blocks 32..2079)
__global__ __launch_bounds__(256) void k_pe(
    const int* __restrict__ x, const float* __restrict__ emb,
    const float* __restrict__ Wt, const float* __restrict__ bt,
    const float* __restrict__ whh, const float* __restrict__ wo,
    float* __restrict__ z, u16* __restrict__ whh16, u16* __restrict__ wo16) {
  __shared__ int toks[256];
  __shared__ float xrep[256];
  int tid = threadIdx.x;
  if (blockIdx.x < 32) {
    int b = blockIdx.x;
    toks[tid] = x[b * 256 + tid];
    __syncthreads();
    float acc = 0.f;
#pragma unroll 8
    for (int s = 0; s < 256; ++s) acc += emb[toks[s] * 256 + tid];
    xrep[tid] = acc * (1.f / 256.f);
    __syncthreads();
    float zacc = bt[tid];
    const float4* wr = (const float4*)(Wt + tid * 256);
#pragma unroll 8
    for (int c = 0; c < 64; ++c) {
      float4 w4 = wr[c];
      zacc += w4.x * xrep[c * 4 + 0] + w4.y * xrep[c * 4 + 1] +
              w4.z * xrep[c * 4 + 2] + w4.w * xrep[c * 4 + 3];
    }
    z[b * 256 + tid] = tanhf(zacc);
  } else {
    int idx = (blockIdx.x - 32) * 256 + tid;
    const int total = 768 * 256 + 32000 * 256;  // 8388608
    for (int i = idx; i < total; i += 2048 * 256) {
      if (i < 768 * 256) whh16[i] = f2h_bits(whh[i]);
      else               wo16[i - 768 * 256] = f2h_bits(wo[i - 768 * 256]);
    }
  }
}

// ---------------- gx2[(t*32+b)*768 + j] = W_ih@(dec_emb[y]+z) + b_ih -------
// fp32 tiled GEMM, output TRANSPOSED for the scan: N=4096 rows x 768 cols
__global__ __launch_bounds__(256, 2) void k_gx(
    const float* __restrict__ W_ih, const float* __restrict__ b_ih,
    const float* __restrict__ dec_emb, const int* __restrict__ y_in,
    const float* __restrict__ z, float* __restrict__ gx2) {
  __shared__ float sA[32][68];  // [k][n]  (dec_emb+z side)
  __shared__ float sB[32][68];  // [k][j]  (W_ih side)
  __shared__ int stok[64];
  int tid = threadIdx.x;
  int jt = blockIdx.x % 12, nt = blockIdx.x / 12;
  int j0 = jt * 64, n0 = nt * 64;
  if (tid < 64) {
    int n = n0 + tid;
    stok[tid] = y_in[(n & 31) * 128 + (n >> 5)];
  }
  float acc[4][4] = {};
  int tn = tid & 15, tj = tid >> 4;  // tj: n-subrow group, tn: j-subcol group
  for (int kc = 0; kc < 8; ++kc) {
    int k0 = kc * 32;
    __syncthreads();
#pragma unroll
    for (int qq = 0; qq < 2; ++qq) {
      int q = tid + qq * 256;      // 0..511 float4 slots
      int rr = q >> 3, kq = q & 7; // rr: local row (n or j), kq: float4 within 32k
      int b = (n0 + rr) & 31;
      float4 ve = *(const float4*)&dec_emb[stok[rr] * 256 + k0 + kq * 4];
      float4 vz = *(const float4*)&z[b * 256 + k0 + kq * 4];
      sA[kq * 4 + 0][rr] = ve.x + vz.x; sA[kq * 4 + 1][rr] = ve.y + vz.y;
      sA[kq * 4 + 2][rr] = ve.z + vz.z; sA[kq * 4 + 3][rr] = ve.w + vz.w;
      float4 vw = *(const float4*)&W_ih[(j0 + rr) * 256 + k0 + kq * 4];
      sB[kq * 4 + 0][rr] = vw.x; sB[kq * 4 + 1][rr] = vw.y;
      sB[kq * 4 + 2][rr] = vw.z; sB[kq * 4 + 3][rr] = vw.w;
    }
    __syncthreads();
#pragma unroll
    for (int k = 0; k < 32; ++k) {
      float4 a4 = *(const float4*)&sA[k][tj * 4];
      float4 b4 = *(const float4*)&sB[k][tn * 4];
      float av[4] = {a4.x, a4.y, a4.z, a4.w};
      float bv[4] = {b4.x, b4.y, b4.z, b4.w};
#pragma unroll
      for (int i = 0; i < 4; ++i)
#pragma unroll
        for (int j2 = 0; j2 < 4; ++j2) acc[i][j2] += av[i] * bv[j2];
    }
  }
  float4 bi = *(const float4*)&b_ih[j0 + tn * 4];
#pragma unroll
  for (int i = 0; i < 4; ++i) {
    int n = n0 + tj * 4 + i;
    float4 o;
    o.x = acc[i][0] + bi.x; o.y = acc[i][1] + bi.y;
    o.z = acc[i][2] + bi.z; o.w = acc[i][3] + bi.w;
    *(float4*)&gx2[n * 768 + j0 + tn * 4] = o;
  }
}

// ---------------- GRU scan: 32 independent blocks (one per batch b) --------
// 512 thr: j = tid&255 (hidden unit), half = tid>>8 (K half).
// W_hh rows {j, 256+j, 512+j} x K-half live in registers (192 VGPR fp16).
// h lives in LDS; per-step GEMV via v_dot2_f32_f16. Hs row = t*32+b.
__global__ __launch_bounds__(512, 2) void k_scan(
    const u16* __restrict__ whh16, const float* __restrict__ b_hh,
    const float* __restrict__ gx2, u16* __restrict__ Hs) {
  int b = blockIdx.x;
  int tid = threadIdx.x;
  int j = tid & 255;
  int half = tid >> 8;

  __shared__ __align__(16) u16 h16[256];
  __shared__ float part[3][256];

  f16x2 w[3][64];
#pragma unroll
  for (int g = 0; g < 3; ++g) {
    const u16* wr = whh16 + (g * 256 + j) * 256 + half * 128;
#pragma unroll
    for (int c = 0; c < 16; ++c) {
      union { f16x8 v8; f16x2 v2[4]; } uu;
      uu.v8 = *(const f16x8*)(wr + c * 8);
      w[g][c * 4 + 0] = uu.v2[0];
      w[g][c * 4 + 1] = uu.v2[1];
      w[g][c * 4 + 2] = uu.v2[2];
      w[g][c * 4 + 3] = uu.v2[3];
    }
  }
  float bh0 = 0.f, bh1 = 0.f, bh2 = 0.f;
  if (half == 0) {
    bh0 = b_hh[j]; bh1 = b_hh[256 + j]; bh2 = b_hh[512 + j];
  }
  if (tid < 256) h16[tid] = 0;  // h = 0
  __syncthreads();

  float h_carry = 0.f;  // fp32 carry of h[j] (half 0 only)
  for (int t = 0; t < 128; ++t) {
    float xr = 0.f, xu = 0.f, xn = 0.f;
    if (half == 0) {  // issue early; consumed after the dot phase
      const float* gp = gx2 + (t * 32 + b) * 768 + j;
      xr = gp[0]; xu = gp[256]; xn = gp[512];
    }
    float a0 = 0.f, a1 = 0.f, a2 = 0.f;
    const f16x8* hv = (const f16x8*)h16;
#pragma unroll
    for (int c = 0; c < 16; ++c) {
      union { f16x8 v8; f16x2 v2[4]; } hu;
      hu.v8 = hv[half * 16 + c];
#pragma unroll
      for (int p = 0; p < 4; ++p) {
        f16x2 hp = hu.v2[p];
        a0 = FDOT2(w[0][c * 4 + p], hp, a0);
        a1 = FDOT2(w[1][c * 4 + p], hp, a1);
        a2 = FDOT2(w[2][c * 4 + p], hp, a2);
      }
    }
    if (half == 1) {
      part[0][j] = a0; part[1][j] = a1; part[2][j] = a2;
    }
    __syncthreads();
    if (half == 0) {
      float gr = a0 + part[0][j] + bh0;
      float gu = a1 + part[1][j] + bh1;
      float gn = a2 + part[2][j] + bh2;
      float r = 1.f / (1.f + expf(-(xr + gr)));
      float u = 1.f / (1.f + expf(-(xu + gu)));
      float n = tanhf(xn + r * gn);
      float h_new = (1.f - u) * n + u * h_carry;
      h_carry = h_new;
      u16 hh = f2h_bits(h_new);
      h16[j] = hh;
      Hs[(t * 32 + b) * 256 + j] = hh;  // t-major row
    }
    __syncthreads();
  }
}

// ---------------- projection: out = Hs @ Wo^T + bo -------------------------
// 1000 blocks = 250 nt (128 cols) x 4 mq (1024 rows). 512 thr, 128 KB LDS.
// Wo tile staged into LDS ONCE per block; 8 x 128-row Hs sub-tiles with
// global->reg prefetch; NT fp32 stores. Write-bound by design.
__global__ __launch_bounds__(512, 2) void k_proj2(
    const u16* __restrict__ Hs, const u16* __restrict__ wo16,
    const float* __restrict__ bo, float* __restrict__ out) {
  __shared__ __align__(16) u16 W[4][8192];    // 64 KB: wo tile 128x256
  __shared__ __align__(16) u16 Hld[4][8192];  // 64 KB: Hs sub-tile 128x256
  int tid = threadIdx.x;
  int wave = tid >> 6, lane = tid & 63;
  int wm = wave >> 1, wn = wave & 1;  // wm: 32-row group, wn: 64-col group
  int mq = blockIdx.x & 3;
  int nt = blockIdx.x >> 2;
  int v0 = nt << 7;
  int mbase = mq << 10;

  // ---- stage wo tile + Hs sub-tile 0 (chunk-swizzled granules) ----
#pragma unroll
  for (int q = 0; q < 8; ++q) {
    int gidx = q * 512 + tid;  // 4096 granules of 16 B
    int chunk = gidx >> 10;
    int g2 = gidx & 1023;
    int row = g2 >> 3, kg = g2 & 7;
    int pg = (g2 & ~7) | (kg ^ (row & 7));
    *(f16x8*)&W[chunk][pg * 8] =
        *(const f16x8*)(wo16 + (v0 + row) * 256 + chunk * 64 + kg * 8);
    *(f16x8*)&Hld[chunk][pg * 8] =
        *(const f16x8*)(Hs + (mbase + row) * 256 + chunk * 64 + kg * 8);
  }
  __syncthreads();

  float bias[4];
#pragma unroll
  for (int j2 = 0; j2 < 4; ++j2)
    bias[j2] = bo[v0 + wn * 64 + j2 * 16 + (lane & 15)];

  f16x8 va[8];
  for (int i = 0; i < 8; ++i) {
    if (i < 7) {  // prefetch next Hs sub-tile into regs (latency under MFMA)
      const u16* src = Hs + (mbase + (i + 1) * 128) * 256;
#pragma unroll
      for (int q = 0; q < 8; ++q) {
        int gidx = q * 512 + tid;
        int chunk = gidx >> 10;
        int g2 = gidx & 1023;
        int row = g2 >> 3, kg = g2 & 7;
        va[q] = *(const f16x8*)(src + row * 256 + chunk * 64 + kg * 8);
      }
    }
    f32x4 acc[2][4];
#pragma unroll
    for (int i2 = 0; i2 < 2; ++i2)
#pragma unroll
      for (int j2 = 0; j2 < 4; ++j2) acc[i2][j2] = (f32x4){0.f, 0.f, 0.f, 0.f};
#pragma unroll
    for (int kc = 0; kc < 4; ++kc) {
#pragma unroll
      for (int ks = 0; ks < 2; ++ks) {
        int kg = ks * 4 + (lane >> 4);
        f16x8 af[2], bf[4];
#pragma unroll
        for (int i2 = 0; i2 < 2; ++i2) {
          int row = wm * 32 + i2 * 16 + (lane & 15);
          af[i2] = *(const f16x8*)&Hld[kc][(row * 8 + (kg ^ (row & 7))) * 8];
        }
#pragma unroll
        for (int j2 = 0; j2 < 4; ++j2) {
          int vrow = wn * 64 + j2 * 16 + (lane & 15);
          bf[j2] = *(const f16x8*)&W[kc][(vrow * 8 + (kg ^ (vrow & 7))) * 8];
        }
#pragma unroll
        for (int i2 = 0; i2 < 2; ++i2)
#pragma unroll
          for (int j2 = 0; j2 < 4; ++j2)
            acc[i2][j2] = __builtin_amdgcn_mfma_f32_16x16x32_f16(
                af[i2], bf[j2], acc[i2][j2], 0, 0, 0);
      }
    }
    // ---- epilogue: n = t*32+b -> out[(b*128+t), v] ----
    int vcol = v0 + wn * 64 + (lane & 15);
    int nb = mbase + i * 128 + wm * 32 + (lane >> 4) * 4;
#pragma unroll
    for (int i2 = 0; i2 < 2; ++i2) {
#pragma unroll
      for (int j2 = 0; j2 < 4; ++j2) {
#pragma unroll
        for (int r = 0; r < 4; ++r) {
          int n = nb + i2 * 16 + r;
          long orow = (long)(n & 31) * 128 + (n >> 5);
          __builtin_nontemporal_store(acc[i2][j2][r] + bias[j2],
                                      &out[orow * 32000 + vcol + j2 * 16]);
        }
      }
    }
    __syncthreads();  // all Hld reads of this sub-tile done
    if (i < 7) {
#pragma unroll
      for (int q = 0; q < 8; ++q) {
        int gidx = q * 512 + tid;
        int chunk = gidx >> 10;
        int g2 = gidx & 1023;
        int row = g2 >> 3, kg = g2 & 7;
        int pg = (g2 & ~7) | (kg ^ (row & 7));
        *(f16x8*)&Hld[chunk][pg * 8] = va[q];
      }
      __syncthreads();  // Hld refilled & visible
    }
  }
}

// ---------------------------------------------------------------------------
extern "C" void kernel_launch(void* const* d_in, const int* in_sizes, int n_in,
                              void* d_out, int out_size, void* d_ws, size_t ws_size,
                              hipStream_t stream) {
  const int*   x       = (const int*)d_in[0];
  const int*   y_in    = (const int*)d_in[1];
  const float* emb     = (const float*)d_in[2];
  const float* dec_emb = (const float*)d_in[3];
  const float* Wt      = (const float*)d_in[4];
  const float* bt      = (const float*)d_in[5];
  const float* W_ih    = (const float*)d_in[6];
  const float* W_hh    = (const float*)d_in[7];
  const float* b_ih    = (const float*)d_in[8];
  const float* b_hh    = (const float*)d_in[9];
  const float* Wo      = (const float*)d_in[10];
  const float* bo      = (const float*)d_in[11];
  float* out = (float*)d_out;
  char* ws = (char*)d_ws;

  float* zbuf     = (float*)(ws + 33024);      // 32*256*4   = 32768
  u16*   Hs       = (u16*)(ws + 98560);        // 4096*256*2 = 2097152
  u16*   whh16    = (u16*)(ws + 2195712);      // 768*256*2  = 393216
  u16*   wo16     = (u16*)(ws + 2588928);      // 32000*256*2= 16384000
  float* gx2      = (float*)(ws + 18972928);   // 4096*768*4 = 12582912
  // total: 31555840 bytes

  k_pe<<<2080, 256, 0, stream>>>(x, emb, Wt, bt, W_hh, Wo, zbuf, whh16, wo16);
  k_gx<<<768, 256, 0, stream>>>(W_ih, b_ih, dec_emb, y_in, zbuf, gx2);
  k_scan<<<32, 512, 0, stream>>>(whh16, b_hh, gx2, Hs);
  k_proj2<<<1000, 512, 0, stream>>>(Hs, wo16, bo, out);
}

// Round 8
// 344.210 us; speedup vs baseline: 1.0940x; 1.0940x over previous
//
#include <hip/hip_runtime.h>

// ---------------------------------------------------------------------------
// TemperSeq2Seq: enc mean-pool -> tanh linear -> 128-step GRU -> 32000-proj
// B=32, S_SRC=256, S_DEC=128, H=256, V=32000
// Megakernel v2: scan blocks 0..31 (W_hh reg-resident, raw ds-barriers,
// gx prefetch x4) + proj blocks 32..8031 (flag-gated, dbuf LDS, NT stores).
// ---------------------------------------------------------------------------

typedef __attribute__((ext_vector_type(8))) _Float16 f16x8;
typedef __attribute__((ext_vector_type(2))) _Float16 f16x2;
typedef __attribute__((ext_vector_type(4))) float f32x4;
typedef unsigned short u16;

__device__ __forceinline__ u16 f2h_bits(float v) {
  _Float16 h = (_Float16)v;
  return __builtin_bit_cast(u16, h);
}

#if __has_builtin(__builtin_amdgcn_fdot2)
#define FDOT2(a, b, c) __builtin_amdgcn_fdot2((a), (b), (c), false)
#else
#define FDOT2(a, b, c) \
  ((c) + (float)(a)[0] * (float)(b)[0] + (float)(a)[1] * (float)(b)[1])
#endif

// ---------------- fused: {enc mean-pool + z} (blocks 0..31) ----------------
//                  {fp32->fp16 W_hh/Wo convert} (blocks 32..2079)
__global__ __launch_bounds__(256) void k_pe(
    const int* __restrict__ x, const float* __restrict__ emb,
    const float* __restrict__ Wt, const float* __restrict__ bt,
    const float* __restrict__ whh, const float* __restrict__ wo,
    float* __restrict__ z, u16* __restrict__ whh16, u16* __restrict__ wo16) {
  __shared__ int toks[256];
  __shared__ float xrep[256];
  int tid = threadIdx.x;
  if (blockIdx.x < 32) {
    int b = blockIdx.x;
    toks[tid] = x[b * 256 + tid];
    __syncthreads();
    float acc = 0.f;
#pragma unroll 8
    for (int s = 0; s < 256; ++s) acc += emb[toks[s] * 256 + tid];
    xrep[tid] = acc * (1.f / 256.f);
    __syncthreads();
    float zacc = bt[tid];
    const float4* wr = (const float4*)(Wt + tid * 256);
#pragma unroll 8
    for (int c = 0; c < 64; ++c) {
      float4 w4 = wr[c];
      zacc += w4.x * xrep[c * 4 + 0] + w4.y * xrep[c * 4 + 1] +
              w4.z * xrep[c * 4 + 2] + w4.w * xrep[c * 4 + 3];
    }
    z[b * 256 + tid] = tanhf(zacc);
  } else {
    int idx = (blockIdx.x - 32) * 256 + tid;
    const int total = 768 * 256 + 32000 * 256;  // 8388608
    for (int i = idx; i < total; i += 2048 * 256) {
      if (i < 768 * 256) whh16[i] = f2h_bits(whh[i]);
      else               wo16[i - 768 * 256] = f2h_bits(wo[i - 768 * 256]);
    }
  }
}

// ---------------- gx2[(t*32+b)*768 + j] = W_ih@(dec_emb[y]+z) + b_ih -------
// fp32 tiled GEMM, output TRANSPOSED for the scan: N=4096 rows x 768 cols
__global__ __launch_bounds__(256, 2) void k_gx(
    const float* __restrict__ W_ih, const float* __restrict__ b_ih,
    const float* __restrict__ dec_emb, const int* __restrict__ y_in,
    const float* __restrict__ z, float* __restrict__ gx2) {
  __shared__ float sA[32][68];  // [k][n]  (dec_emb+z side)
  __shared__ float sB[32][68];  // [k][j]  (W_ih side)
  __shared__ int stok[64];
  int tid = threadIdx.x;
  int jt = blockIdx.x % 12, nt = blockIdx.x / 12;
  int j0 = jt * 64, n0 = nt * 64;
  if (tid < 64) {
    int n = n0 + tid;
    stok[tid] = y_in[(n & 31) * 128 + (n >> 5)];
  }
  float acc[4][4] = {};
  int tn = tid & 15, tj = tid >> 4;
  for (int kc = 0; kc < 8; ++kc) {
    int k0 = kc * 32;
    __syncthreads();
#pragma unroll
    for (int qq = 0; qq < 2; ++qq) {
      int q = tid + qq * 256;
      int rr = q >> 3, kq = q & 7;
      int b = (n0 + rr) & 31;
      float4 ve = *(const float4*)&dec_emb[stok[rr] * 256 + k0 + kq * 4];
      float4 vz = *(const float4*)&z[b * 256 + k0 + kq * 4];
      sA[kq * 4 + 0][rr] = ve.x + vz.x; sA[kq * 4 + 1][rr] = ve.y + vz.y;
      sA[kq * 4 + 2][rr] = ve.z + vz.z; sA[kq * 4 + 3][rr] = ve.w + vz.w;
      float4 vw = *(const float4*)&W_ih[(j0 + rr) * 256 + k0 + kq * 4];
      sB[kq * 4 + 0][rr] = vw.x; sB[kq * 4 + 1][rr] = vw.y;
      sB[kq * 4 + 2][rr] = vw.z; sB[kq * 4 + 3][rr] = vw.w;
    }
    __syncthreads();
#pragma unroll
    for (int k = 0; k < 32; ++k) {
      float4 a4 = *(const float4*)&sA[k][tj * 4];
      float4 b4 = *(const float4*)&sB[k][tn * 4];
      float av[4] = {a4.x, a4.y, a4.z, a4.w};
      float bv[4] = {b4.x, b4.y, b4.z, b4.w};
#pragma unroll
      for (int i = 0; i < 4; ++i)
#pragma unroll
        for (int j2 = 0; j2 < 4; ++j2) acc[i][j2] += av[i] * bv[j2];
    }
  }
  float4 bi = *(const float4*)&b_ih[j0 + tn * 4];
#pragma unroll
  for (int i = 0; i < 4; ++i) {
    int n = n0 + tj * 4 + i;
    float4 o;
    o.x = acc[i][0] + bi.x; o.y = acc[i][1] + bi.y;
    o.z = acc[i][2] + bi.z; o.w = acc[i][3] + bi.w;
    *(float4*)&gx2[n * 768 + j0 + tn * 4] = o;
  }
}

// ---------------- MEGAKERNEL v2 --------------------------------------------
// One scan step, statically unrolled x4 for register-resident gx prefetch.
// Raw s_barrier + lgkmcnt(0): Hs stores / gx loads stay in flight across
// steps; full vmcnt(0) drain only on flag steps (cross-XCD release).
#define SCAN_BODY(T, S)                                                      \
  {                                                                          \
    float a0 = 0.f, a1 = 0.f, a2 = 0.f;                                      \
    const f16x8* hv = (const f16x8*)h16;                                     \
    _Pragma("unroll")                                                        \
    for (int c = 0; c < 16; ++c) {                                           \
      union { f16x8 v8; f16x2 v2[4]; } hu;                                   \
      hu.v8 = hv[half * 16 + c];                                             \
      _Pragma("unroll")                                                      \
      for (int p = 0; p < 4; ++p) {                                          \
        f16x2 hp = hu.v2[p];                                                 \
        a0 = FDOT2(w[0][c * 4 + p], hp, a0);                                 \
        a1 = FDOT2(w[1][c * 4 + p], hp, a1);                                 \
        a2 = FDOT2(w[2][c * 4 + p], hp, a2);                                 \
      }                                                                      \
    }                                                                        \
    if (half == 1) { part[j] = a0; part[256 + j] = a1; part[512 + j] = a2; } \
    asm volatile("s_waitcnt lgkmcnt(0)" ::: "memory");                       \
    __builtin_amdgcn_s_barrier();                                            \
    if (half == 0) {                                                         \
      float gr = a0 + part[j] + bh0;                                         \
      float gu = a1 + part[256 + j] + bh1;                                   \
      float gn = a2 + part[512 + j] + bh2;                                   \
      float r = 1.f / (1.f + expf(-(pxr##S + gr)));                          \
      float u = 1.f / (1.f + expf(-(pxu##S + gu)));                          \
      float n = tanhf(pxn##S + r * gn);                                      \
      float h_new = (1.f - u) * n + u * h_carry;                             \
      h_carry = h_new;                                                       \
      u16 hh = f2h_bits(h_new);                                              \
      h16[j] = hh;                                                           \
      Hs[((T) * 32 + b) * 256 + j] = hh;                                     \
      if ((T) + 4 < 128) {                                                   \
        const float* gp = gx2 + (((T) + 4) * 32 + b) * 768 + j;              \
        pxr##S = gp[0]; pxu##S = gp[256]; pxn##S = gp[512];                  \
      }                                                                      \
    }                                                                        \
    if (((T) & 3) == 3) {                                                    \
      asm volatile("s_waitcnt vmcnt(0) lgkmcnt(0)" ::: "memory");            \
      __builtin_amdgcn_s_barrier();                                          \
      if (tid == 0) {                                                        \
        __builtin_amdgcn_fence(__ATOMIC_RELEASE, "agent");                   \
        __hip_atomic_store(&flags[b * 4], (unsigned)((T) + 1),               \
                           __ATOMIC_RELAXED, __HIP_MEMORY_SCOPE_AGENT);      \
      }                                                                      \
    } else {                                                                 \
      asm volatile("s_waitcnt lgkmcnt(0)" ::: "memory");                     \
      __builtin_amdgcn_s_barrier();                                          \
    }                                                                        \
  }

__global__ __launch_bounds__(512, 1) void k_mega(
    const u16* __restrict__ whh16, const float* __restrict__ b_hh,
    const float* __restrict__ gx2, u16* __restrict__ Hs,
    const u16* __restrict__ wo16, const float* __restrict__ bo,
    float* __restrict__ out, unsigned* __restrict__ flags) {
  __shared__ __align__(16) u16 sA[2][8192];   // proj dbuf / scan h16+part
  __shared__ __align__(16) u16 sB[2][8192];
  int tid = threadIdx.x;

  if (blockIdx.x < 32) {
    // =================== GRU scan ===================
    u16* h16 = &sA[0][0];             // 256 u16
    float* part = (float*)&sB[0][0];  // 3*256 floats
    int b = blockIdx.x;
    int j = tid & 255;
    int half = tid >> 8;

    f16x2 w[3][64];
#pragma unroll
    for (int g = 0; g < 3; ++g) {
      const u16* wr = whh16 + (g * 256 + j) * 256 + half * 128;
#pragma unroll
      for (int c = 0; c < 16; ++c) {
        union { f16x8 v8; f16x2 v2[4]; } uu;
        uu.v8 = *(const f16x8*)(wr + c * 8);
        w[g][c * 4 + 0] = uu.v2[0];
        w[g][c * 4 + 1] = uu.v2[1];
        w[g][c * 4 + 2] = uu.v2[2];
        w[g][c * 4 + 3] = uu.v2[3];
      }
    }
    float bh0 = 0.f, bh1 = 0.f, bh2 = 0.f;
    float pxr0 = 0.f, pxu0 = 0.f, pxn0 = 0.f;
    float pxr1 = 0.f, pxu1 = 0.f, pxn1 = 0.f;
    float pxr2 = 0.f, pxu2 = 0.f, pxn2 = 0.f;
    float pxr3 = 0.f, pxu3 = 0.f, pxn3 = 0.f;
    if (half == 0) {
      bh0 = b_hh[j]; bh1 = b_hh[256 + j]; bh2 = b_hh[512 + j];
      const float* g0 = gx2 + (0 * 32 + b) * 768 + j;
      const float* g1 = gx2 + (1 * 32 + b) * 768 + j;
      const float* g2 = gx2 + (2 * 32 + b) * 768 + j;
      const float* g3 = gx2 + (3 * 32 + b) * 768 + j;
      pxr0 = g0[0]; pxu0 = g0[256]; pxn0 = g0[512];
      pxr1 = g1[0]; pxu1 = g1[256]; pxn1 = g1[512];
      pxr2 = g2[0]; pxu2 = g2[256]; pxn2 = g2[512];
      pxr3 = g3[0]; pxu3 = g3[256]; pxn3 = g3[512];
    }
    if (tid < 256) h16[tid] = 0;  // h = 0
    float h_carry = 0.f;
    __syncthreads();

    for (int tb = 0; tb < 128; tb += 4) {
      SCAN_BODY(tb + 0, 0);
      SCAN_BODY(tb + 1, 1);
      SCAN_BODY(tb + 2, 2);
      SCAN_BODY(tb + 3, 3);
    }
  } else {
    // =================== projection tile ===================
    int pid = blockIdx.x - 32;
    int mt = pid / 250, nt = pid % 250;
    int m0 = mt << 7, v0 = nt << 7;
    int wave = tid >> 6, lane = tid & 63;
    int wm = wave >> 1, wn = wave & 1;

    // ---- wait until scan rows [m0, m0+128) are published ----
    {
      unsigned need = (unsigned)(4 * mt + 4);
      if (tid < 64) {
        while (true) {
          unsigned f = __hip_atomic_load(&flags[(tid & 31) * 4],
                                         __ATOMIC_RELAXED,
                                         __HIP_MEMORY_SCOPE_AGENT);
          if (__all(f >= need)) break;
          __builtin_amdgcn_s_sleep(8);
        }
        __builtin_amdgcn_fence(__ATOMIC_ACQUIRE, "agent");
      }
      __syncthreads();
    }

    f32x4 acc[2][4];
#pragma unroll
    for (int i = 0; i < 2; ++i)
#pragma unroll
      for (int j2 = 0; j2 < 4; ++j2) acc[i][j2] = (f32x4){0.f, 0.f, 0.f, 0.f};

    f16x8 va[2], vb[2];
#define LOADC(kc_)                                                        \
    {                                                                     \
      int kb = (kc_) << 6;                                                \
      _Pragma("unroll") for (int q = 0; q < 2; ++q) {                     \
        int gr = q * 512 + tid;                                           \
        int row = gr >> 3, kg = gr & 7;                                   \
        va[q] = *(const f16x8*)(Hs + (m0 + row) * 256 + kb + kg * 8);     \
        vb[q] = *(const f16x8*)(wo16 + (v0 + row) * 256 + kb + kg * 8);   \
      }                                                                   \
    }
#define STORELDS(bsel_)                                                   \
    {                                                                     \
      _Pragma("unroll") for (int q = 0; q < 2; ++q) {                     \
        int gr = q * 512 + tid;                                           \
        int row = gr >> 3, kg = gr & 7;                                   \
        int pg = (gr & ~7) | (kg ^ (row & 7));                            \
        *(f16x8*)&sA[bsel_][pg * 8] = va[q];                              \
        *(f16x8*)&sB[bsel_][pg * 8] = vb[q];                              \
      }                                                                   \
    }

    LOADC(0);
    STORELDS(0);
    __syncthreads();

    for (int kc = 0; kc < 4; ++kc) {
      int bsel = kc & 1;
      if (kc < 3) LOADC(kc + 1);
#pragma unroll
      for (int ks = 0; ks < 2; ++ks) {
        f16x8 af[2], bf[4];
        int kg = ks * 4 + (lane >> 4);
#pragma unroll
        for (int i = 0; i < 2; ++i) {
          int row = wm * 32 + i * 16 + (lane & 15);
          af[i] = *(const f16x8*)&sA[bsel][(row * 8 + (kg ^ (row & 7))) * 8];
        }
#pragma unroll
        for (int j2 = 0; j2 < 4; ++j2) {
          int vrow = wn * 64 + j2 * 16 + (lane & 15);
          bf[j2] = *(const f16x8*)&sB[bsel][(vrow * 8 + (kg ^ (vrow & 7))) * 8];
        }
#pragma unroll
        for (int i = 0; i < 2; ++i)
#pragma unroll
          for (int j2 = 0; j2 < 4; ++j2)
            acc[i][j2] = __builtin_amdgcn_mfma_f32_16x16x32_f16(
                af[i], bf[j2], acc[i][j2], 0, 0, 0);
      }
      if (kc < 3) STORELDS(bsel ^ 1);
      __syncthreads();
    }
#undef LOADC
#undef STORELDS

    int vcol = v0 + wn * 64 + (lane & 15);
    int nbase = m0 + wm * 32 + (lane >> 4) * 4;
#pragma unroll
    for (int i = 0; i < 2; ++i) {
#pragma unroll
      for (int j2 = 0; j2 < 4; ++j2) {
        int v = vcol + j2 * 16;
        float bias = bo[v];
#pragma unroll
        for (int r = 0; r < 4; ++r) {
          int n = nbase + i * 16 + r;          // n = t*32 + b
          long orow = (long)(n & 31) * 128 + (n >> 5);
          __builtin_nontemporal_store(acc[i][j2][r] + bias,
                                      &out[orow * 32000 + v]);
        }
      }
    }
  }
}

// ---------------------------------------------------------------------------
extern "C" void kernel_launch(void* const* d_in, const int* in_sizes, int n_in,
                              void* d_out, int out_size, void* d_ws, size_t ws_size,
                              hipStream_t stream) {
  const int*   x       = (const int*)d_in[0];
  const int*   y_in    = (const int*)d_in[1];
  const float* emb     = (const float*)d_in[2];
  const float* dec_emb = (const float*)d_in[3];
  const float* Wt      = (const float*)d_in[4];
  const float* bt      = (const float*)d_in[5];
  const float* W_ih    = (const float*)d_in[6];
  const float* W_hh    = (const float*)d_in[7];
  const float* b_ih    = (const float*)d_in[8];
  const float* b_hh    = (const float*)d_in[9];
  const float* Wo      = (const float*)d_in[10];
  const float* bo      = (const float*)d_in[11];
  float* out = (float*)d_out;
  char* ws = (char*)d_ws;

  unsigned* flags = (unsigned*)(ws + 0);       // 32 slots x 16B = 512 B
  float* zbuf     = (float*)(ws + 33024);      // 32*256*4   = 32768
  u16*   Hs       = (u16*)(ws + 98560);        // 4096*256*2 = 2097152
  u16*   whh16    = (u16*)(ws + 2195712);      // 768*256*2  = 393216
  u16*   wo16     = (u16*)(ws + 2588928);      // 32000*256*2= 16384000
  float* gx2      = (float*)(ws + 18972928);   // 4096*768*4 = 12582912
  // total: 31555840 bytes

  (void)hipMemsetAsync(flags, 0, 512, stream);
  k_pe<<<2080, 256, 0, stream>>>(x, emb, Wt, bt, W_hh, Wo, zbuf, whh16, wo16);
  k_gx<<<768, 256, 0, stream>>>(W_ih, b_ih, dec_emb, y_in, zbuf, gx2);
  k_mega<<<8032, 512, 0, stream>>>(whh16, b_hh, gx2, Hs, wo16, bo, out, flags);
}